// Round 1
// baseline (63.413 us; speedup 1.0000x reference)
//
#include <hip/hip_runtime.h>

#define IMG 512
#define NPIX (IMG*IMG)

__device__ __forceinline__ float ldg_guard(const float* p, int r, int c){
  return ((unsigned)r < (unsigned)IMG && (unsigned)c < (unsigned)IMG) ? p[r*IMG+c] : 0.f;
}

// ---------------------------------------------------------------------------
// Kernel A: lag Gram sums L_ab[dy,dx] for (x0x0,x0x1,x1x1,x0e,x1e,ee),
// dy,dx in [-2,2]. 256 blocks x 256 thr; blocks [0,128): batch 0, [128,256): b1.
// Each thread: one column, 8 rows, 5x5 rolling window per map.
// Output: per-block partials part[blk*150 + tensor*25 + lag] (no atomics).
// ---------------------------------------------------------------------------
__global__ __launch_bounds__(256,1) void gram_kernel(const float* __restrict__ x,
                                                     const float* __restrict__ e,
                                                     float* __restrict__ part){
  const int b   = blockIdx.x >> 7;
  const int tin = ((blockIdx.x & 127) << 8) | threadIdx.x;   // 0..32767
  const int col = tin & (IMG-1);
  const int r0  = (tin >> 9) << 3;                           // chunk*8
  const float* x0 = x + (size_t)b*2*NPIX;
  const float* x1 = x0 + NPIX;
  const float* ee = e + (size_t)b*NPIX;

  float acc[6][25];
#pragma unroll
  for (int t=0;t<6;t++)
#pragma unroll
    for (int l=0;l<25;l++) acc[t][l]=0.f;

  float w0[5][5], w1[5][5], wE[5][5];
#pragma unroll
  for (int r=0;r<5;r++){
    int rr = r0-2+r;
#pragma unroll
    for (int c=0;c<5;c++){
      int cc = col-2+c;
      w0[r][c]=ldg_guard(x0,rr,cc);
      w1[r][c]=ldg_guard(x1,rr,cc);
      wE[r][c]=ldg_guard(ee,rr,cc);
    }
  }
#pragma unroll
  for (int s=0;s<8;s++){
    float a0=w0[2][2], a1v=w1[2][2], aE=wE[2][2];
#pragma unroll
    for (int r=0;r<5;r++)
#pragma unroll
      for (int c=0;c<5;c++){
        int l=r*5+c;
        acc[0][l] += a0 *w0[r][c];
        acc[1][l] += a0 *w1[r][c];
        acc[2][l] += a1v*w1[r][c];
        acc[3][l] += a0 *wE[r][c];
        acc[4][l] += a1v*wE[r][c];
        acc[5][l] += aE *wE[r][c];
      }
    if (s<7){
#pragma unroll
      for (int r=0;r<4;r++)
#pragma unroll
        for (int c=0;c<5;c++){ w0[r][c]=w0[r+1][c]; w1[r][c]=w1[r+1][c]; wE[r][c]=wE[r+1][c]; }
      int rr = r0+3+s;
#pragma unroll
      for (int c=0;c<5;c++){
        int cc = col-2+c;
        w0[4][c]=ldg_guard(x0,rr,cc);
        w1[4][c]=ldg_guard(x1,rr,cc);
        wE[4][c]=ldg_guard(ee,rr,cc);
      }
    }
  }
  // wave reduce -> LDS -> block partial
  __shared__ float red[600];
  const int wv = threadIdx.x >> 6;
  const int lane = threadIdx.x & 63;
#pragma unroll
  for (int t=0;t<6;t++)
#pragma unroll
    for (int l=0;l<25;l++){
      float v = acc[t][l];
      for (int off=32; off; off>>=1) v += __shfl_down(v, off);
      if (lane==0) red[wv*150 + t*25+l] = v;
    }
  __syncthreads();
  for (int i=threadIdx.x; i<150; i+=256)
    part[blockIdx.x*150 + i] = red[i]+red[150+i]+red[300+i]+red[450+i];
}

// ---------------------------------------------------------------------------
// Kernel B: single block. Reduce partials -> L; build S[c,d], norms, softmax,
// fold proj: M = wproj*attn; fold epilogue conv: A,B (2b x 2o x 9 taps each).
// ---------------------------------------------------------------------------
__global__ __launch_bounds__(256,1) void attn_kernel(const float* __restrict__ part,
                                                     const float* __restrict__ w_conv1,
                                                     const float* __restrict__ w_dw,
                                                     const float* __restrict__ w_ehead,
                                                     const float* __restrict__ w_proj,
                                                     const float* __restrict__ a1,
                                                     float* __restrict__ AB){
  const int tid = threadIdx.x;
  __shared__ float Lred[2][150];
  __shared__ float we_lds[128][9];
  __shared__ float nk_lds[2][128];
  __shared__ float attn_lds[2][8][16][16];
  __shared__ float M_lds[2][2][128];

  for (int i=tid; i<300; i+=256){
    int bb=i/150, li=i%150;
    float s=0.f;
    for (int j=0;j<128;j++) s += part[(bb*128+j)*150 + li];
    Lred[bb][li]=s;
  }
  if (tid<128){
#pragma unroll
    for (int t=0;t<9;t++) we_lds[tid][t]=w_ehead[tid*9+t];
  }
  __syncthreads();

  const int b=tid>>7, h=(tid>>4)&7, c=tid&15;
  const int C=h*16+c;
  const float* Lb  = Lred[b];
  const float* L00=Lb, *L01=Lb+25, *L11=Lb+50, *L0e=Lb+75, *L1e=Lb+100, *Lee=Lb+125;

  float u[9], v[9];
  {
    float wa=w_conv1[C*2+0], wb=w_conv1[C*2+1];
#pragma unroll
    for (int t=0;t<9;t++){ float wd=w_dw[C*9+t]; u[t]=wd*wa; v[t]=wd*wb; }
  }
  float nq2=0.f, nk2=0.f;
#pragma unroll
  for (int t=0;t<9;t++){
    int ty=t/3, tx=t%3;
#pragma unroll
    for (int t2=0;t2<9;t2++){
      int dy=t2/3-ty, dx=t2%3-tx;
      int di=( dy+2)*5+( dx+2);
      int dj=(-dy+2)*5+(-dx+2);
      nq2 += u[t]*u[t2]*L00[di] + u[t]*v[t2]*L01[di] + v[t]*u[t2]*L01[dj] + v[t]*v[t2]*L11[di];
      nk2 += we_lds[C][t]*we_lds[C][t2]*Lee[di];
    }
  }
  nk_lds[b][C]=sqrtf(nk2);
  float P[9];
#pragma unroll
  for (int t2=0;t2<9;t2++){
    float s=0.f;
    int t2y=t2/3, t2x=t2%3;
#pragma unroll
    for (int t=0;t<9;t++){
      int di=(t2y-t/3+2)*5+(t2x-t%3+2);
      s += u[t]*L0e[di] + v[t]*L1e[di];
    }
    P[t2]=s;
  }
  __syncthreads();
  float inv_nq = 1.f/fmaxf(sqrtf(nq2), 1e-12f);
  float a1h=a1[h];
  float lg[16], mx=-1e30f;
#pragma unroll
  for (int d=0; d<16; d++){
    float S=0.f;
#pragma unroll
    for (int t2=0;t2<9;t2++) S += P[t2]*we_lds[h*16+d][t2];
    float l = S*inv_nq/fmaxf(nk_lds[b][h*16+d],1e-12f)*a1h;
    lg[d]=l; mx=fmaxf(mx,l);
  }
  float sum=0.f;
#pragma unroll
  for (int d=0;d<16;d++){ lg[d]=expf(lg[d]-mx); sum+=lg[d]; }
  float inv=1.f/sum;
#pragma unroll
  for (int d=0;d<16;d++) attn_lds[b][h][c][d]=lg[d]*inv;
  __syncthreads();
  for (int i=tid;i<512;i+=256){
    int G=i&127, o=(i>>7)&1, bb=i>>8;
    int hh=G>>4, dd=G&15;
    float s=0.f;
#pragma unroll
    for (int cc=0;cc<16;cc++) s += w_proj[o*128 + hh*16+cc]*attn_lds[bb][hh][cc][dd];
    M_lds[bb][o][G]=s;
  }
  __syncthreads();
  if (tid<36){
    int t=tid%9, o=(tid/9)&1, bb=tid/18;
    float sa=0.f, sb=0.f;
    for (int G=0;G<128;G++){
      float m=M_lds[bb][o][G];
      float wd=w_dw[(128+G)*9+t];
      sa += m*wd*w_conv1[(128+G)*2+0];
      sb += m*wd*w_conv1[(128+G)*2+1];
    }
    AB[(bb*2+o)*9+t]      = sa;
    AB[72 + (bb*2+o)*9+t] = sb;
  }
}

// ---------------------------------------------------------------------------
// Kernel C: out[b,o] = x[b,o] + conv3x3(x0;A[b,o]) + conv3x3(x1;B[b,o]).
// 4 pixels/thread, float4 I/O. 512 blocks x 256 thr.
// ---------------------------------------------------------------------------
__global__ __launch_bounds__(256,1) void out_kernel(const float* __restrict__ x,
                                                    const float* __restrict__ AB,
                                                    float* __restrict__ out){
  const int idx = blockIdx.x*256 + threadIdx.x;   // 131072
  const int b  = idx >> 16;
  const int y  = (idx >> 7) & (IMG-1);
  const int xc = (idx & 127) << 2;
  const float* x0 = x + (size_t)b*2*NPIX;
  const float* x1 = x0 + NPIX;

  float A0[9],A1[9],B0[9],B1[9];
#pragma unroll
  for (int t=0;t<9;t++){
    A0[t]=AB[(b*2+0)*9+t];      A1[t]=AB[(b*2+1)*9+t];
    B0[t]=AB[72+(b*2+0)*9+t];   B1[t]=AB[72+(b*2+1)*9+t];
  }
  float v0[3][6], v1[3][6];
#pragma unroll
  for (int r=0;r<3;r++){
    int yy=y-1+r;
    if ((unsigned)yy < (unsigned)IMG){
      const float* p0=x0+(size_t)yy*IMG;
      const float* p1=x1+(size_t)yy*IMG;
      float4 m0=*(const float4*)(p0+xc);
      float4 m1=*(const float4*)(p1+xc);
      v0[r][1]=m0.x; v0[r][2]=m0.y; v0[r][3]=m0.z; v0[r][4]=m0.w;
      v1[r][1]=m1.x; v1[r][2]=m1.y; v1[r][3]=m1.z; v1[r][4]=m1.w;
      v0[r][0]=(xc>0)?p0[xc-1]:0.f;        v1[r][0]=(xc>0)?p1[xc-1]:0.f;
      v0[r][5]=(xc+4<IMG)?p0[xc+4]:0.f;    v1[r][5]=(xc+4<IMG)?p1[xc+4]:0.f;
    } else {
#pragma unroll
      for (int c2=0;c2<6;c2++){v0[r][c2]=0.f;v1[r][c2]=0.f;}
    }
  }
  float res0[4], res1[4];
#pragma unroll
  for (int i=0;i<4;i++){
    float s0=v0[1][i+1];   // + x[b,0,y,x]
    float s1=v1[1][i+1];   // + x[b,1,y,x]
#pragma unroll
    for (int t=0;t<9;t++){
      int ty=t/3, tx=t%3;
      float g0=v0[ty][i+tx], g1=v1[ty][i+tx];
      s0 += A0[t]*g0 + B0[t]*g1;
      s1 += A1[t]*g0 + B1[t]*g1;
    }
    res0[i]=s0; res1[i]=s1;
  }
  float* o0p = out + ((size_t)(b*2+0)*IMG + y)*IMG + xc;
  float* o1p = out + ((size_t)(b*2+1)*IMG + y)*IMG + xc;
  *(float4*)o0p = make_float4(res0[0],res0[1],res0[2],res0[3]);
  *(float4*)o1p = make_float4(res1[0],res1[1],res1[2],res1[3]);
}

extern "C" void kernel_launch(void* const* d_in, const int* in_sizes, int n_in,
                              void* d_out, int out_size, void* d_ws, size_t ws_size,
                              hipStream_t stream){
  const float* x       = (const float*)d_in[0];
  const float* e       = (const float*)d_in[1];
  const float* w_conv1 = (const float*)d_in[2];
  const float* w_dw    = (const float*)d_in[3];
  const float* w_ehead = (const float*)d_in[4];
  const float* w_proj  = (const float*)d_in[5];
  const float* a1      = (const float*)d_in[6];
  float* ws   = (float*)d_ws;
  float* part = ws;            // 256*150 = 38400 floats
  float* AB   = ws + 38400;    // 144 floats
  float* out  = (float*)d_out;

  hipLaunchKernelGGL(gram_kernel, dim3(256), dim3(256), 0, stream, x, e, part);
  hipLaunchKernelGGL(attn_kernel, dim3(1),   dim3(256), 0, stream, part,
                     w_conv1, w_dw, w_ehead, w_proj, a1, AB);
  hipLaunchKernelGGL(out_kernel,  dim3(512), dim3(256), 0, stream, x, AB, out);
}

// Round 2
// 43.619 us; speedup vs baseline: 1.4538x; 1.4538x over previous
//
#include <hip/hip_runtime.h>

#define IMG 512
#define NPIX (IMG*IMG)

// ---------------------------------------------------------------------------
// Kernel A: lag Gram sums L_ab[dy,dx] for (x0x0,x0x1,x1x1,x0e,x1e,ee),
// dy,dx in [-2,2]. Split by dy across blockIdx.y (5) and batch (blockIdx.z, 2)
// so each thread holds only acc[6][5] = 30 accumulators (no spill; the old
// 6x25+windows version held 230+ floats -> scratch-bound).
// blockIdx.x: 64 = 2 column-halves x 32 row-chunks of 16 rows.
// Output: per-block partials part[((b*5+dyi)*64 + blk)*32 + t*5+dxi].
// ---------------------------------------------------------------------------
__global__ __launch_bounds__(256,2) void gram_kernel(const float* __restrict__ x,
                                                     const float* __restrict__ e,
                                                     float* __restrict__ part){
  const int dyi = blockIdx.y;            // 0..4
  const int dy  = dyi - 2;
  const int b   = blockIdx.z;
  const int col = ((blockIdx.x & 1) << 8) | threadIdx.x;   // 0..511
  const int r0  = (blockIdx.x >> 1) << 4;                  // chunk*16
  const float* x0 = x + (size_t)b*2*NPIX;
  const float* x1 = x0 + NPIX;
  const float* ep = e + (size_t)b*NPIX;

  float acc[6][5];
#pragma unroll
  for (int t=0;t<6;t++)
#pragma unroll
    for (int j=0;j<5;j++) acc[t][j]=0.f;

#pragma unroll 4
  for (int s=0;s<16;s++){
    const int r = r0+s;
    const float a0 = x0[r*IMG+col];
    const float a1v= x1[r*IMG+col];
    const float aE = ep[r*IMG+col];
    const int rb = r+dy;
    if ((unsigned)rb < (unsigned)IMG){
      const float* p0 = x0 + rb*IMG;
      const float* p1 = x1 + rb*IMG;
      const float* pe = ep + rb*IMG;
#pragma unroll
      for (int j=0;j<5;j++){
        const int cc = col-2+j;
        const bool ok = (unsigned)cc < (unsigned)IMG;
        const float b0 = ok ? p0[cc] : 0.f;
        const float b1 = ok ? p1[cc] : 0.f;
        const float be = ok ? pe[cc] : 0.f;
        acc[0][j] += a0 *b0;
        acc[1][j] += a0 *b1;
        acc[2][j] += a1v*b1;
        acc[3][j] += a0 *be;
        acc[4][j] += a1v*be;
        acc[5][j] += aE *be;
      }
    }
  }

  // wave reduce -> LDS -> block partial (30 values)
  __shared__ float red[4][30];
  const int wv   = threadIdx.x >> 6;
  const int lane = threadIdx.x & 63;
#pragma unroll
  for (int t=0;t<6;t++)
#pragma unroll
    for (int j=0;j<5;j++){
      float v = acc[t][j];
      for (int off=32; off; off>>=1) v += __shfl_down(v, off);
      if (lane==0) red[wv][t*5+j] = v;
    }
  __syncthreads();
  if (threadIdx.x < 30){
    const int g = b*5 + dyi;
    part[(size_t)((g*64)+blockIdx.x)*32 + threadIdx.x] =
      red[0][threadIdx.x]+red[1][threadIdx.x]+red[2][threadIdx.x]+red[3][threadIdx.x];
  }
}

// ---------------------------------------------------------------------------
// Kernel B: single block. Reduce partials -> L; build S[c,d], norms, softmax,
// fold proj: M = wproj*attn; fold epilogue conv: A,B (2b x 2o x 9 taps each).
// ---------------------------------------------------------------------------
__global__ __launch_bounds__(256,1) void attn_kernel(const float* __restrict__ part,
                                                     const float* __restrict__ w_conv1,
                                                     const float* __restrict__ w_dw,
                                                     const float* __restrict__ w_ehead,
                                                     const float* __restrict__ w_proj,
                                                     const float* __restrict__ a1,
                                                     float* __restrict__ AB){
  const int tid = threadIdx.x;
  __shared__ float Lred[2][150];
  __shared__ float we_lds[128][9];
  __shared__ float nk_lds[2][128];
  __shared__ float attn_lds[2][8][16][16];
  __shared__ float M_lds[2][2][128];

  for (int i=tid; i<300; i+=256){
    const int bb=i/150, li=i%150;
    const int t=li/25, lag=li%25, dyi=lag/5, dxi=lag%5;
    const int g = bb*5+dyi;
    const float* p = part + (size_t)(g*64)*32 + t*5+dxi;
    float s=0.f;
    for (int j=0;j<64;j++) s += p[j*32];
    Lred[bb][li]=s;
  }
  if (tid<128){
#pragma unroll
    for (int t=0;t<9;t++) we_lds[tid][t]=w_ehead[tid*9+t];
  }
  __syncthreads();

  const int b=tid>>7, h=(tid>>4)&7, c=tid&15;
  const int C=h*16+c;
  const float* Lb  = Lred[b];
  const float* L00=Lb, *L01=Lb+25, *L11=Lb+50, *L0e=Lb+75, *L1e=Lb+100, *Lee=Lb+125;

  float u[9], v[9];
  {
    const float wa=w_conv1[C*2+0], wb=w_conv1[C*2+1];
#pragma unroll
    for (int t=0;t<9;t++){ const float wd=w_dw[C*9+t]; u[t]=wd*wa; v[t]=wd*wb; }
  }
  float nq2=0.f, nk2=0.f;
#pragma unroll
  for (int t=0;t<9;t++){
    const int ty=t/3, tx=t%3;
#pragma unroll
    for (int t2=0;t2<9;t2++){
      const int dy=t2/3-ty, dx=t2%3-tx;
      const int di=( dy+2)*5+( dx+2);
      const int dj=(-dy+2)*5+(-dx+2);
      nq2 += u[t]*u[t2]*L00[di] + u[t]*v[t2]*L01[di] + v[t]*u[t2]*L01[dj] + v[t]*v[t2]*L11[di];
      nk2 += we_lds[C][t]*we_lds[C][t2]*Lee[di];
    }
  }
  nk_lds[b][C]=sqrtf(nk2);
  float P[9];
#pragma unroll
  for (int t2=0;t2<9;t2++){
    float s=0.f;
    const int t2y=t2/3, t2x=t2%3;
#pragma unroll
    for (int t=0;t<9;t++){
      const int di=(t2y-t/3+2)*5+(t2x-t%3+2);
      s += u[t]*L0e[di] + v[t]*L1e[di];
    }
    P[t2]=s;
  }
  __syncthreads();
  const float inv_nq = 1.f/fmaxf(sqrtf(nq2), 1e-12f);
  const float a1h=a1[h];
  float lg[16], mx=-1e30f;
#pragma unroll
  for (int d=0; d<16; d++){
    float S=0.f;
#pragma unroll
    for (int t2=0;t2<9;t2++) S += P[t2]*we_lds[h*16+d][t2];
    const float l = S*inv_nq/fmaxf(nk_lds[b][h*16+d],1e-12f)*a1h;
    lg[d]=l; mx=fmaxf(mx,l);
  }
  float sum=0.f;
#pragma unroll
  for (int d=0;d<16;d++){ lg[d]=expf(lg[d]-mx); sum+=lg[d]; }
  const float inv=1.f/sum;
#pragma unroll
  for (int d=0;d<16;d++) attn_lds[b][h][c][d]=lg[d]*inv;
  __syncthreads();
  for (int i=tid;i<512;i+=256){
    const int G=i&127, o=(i>>7)&1, bb=i>>8;
    const int hh=G>>4, dd=G&15;
    float s=0.f;
#pragma unroll
    for (int cc=0;cc<16;cc++) s += w_proj[o*128 + hh*16+cc]*attn_lds[bb][hh][cc][dd];
    M_lds[bb][o][G]=s;
  }
  __syncthreads();
  if (tid<36){
    const int t=tid%9, o=(tid/9)&1, bb=tid/18;
    float sa=0.f, sb=0.f;
    for (int G=0;G<128;G++){
      const float m=M_lds[bb][o][G];
      const float wd=w_dw[(128+G)*9+t];
      sa += m*wd*w_conv1[(128+G)*2+0];
      sb += m*wd*w_conv1[(128+G)*2+1];
    }
    AB[(bb*2+o)*9+t]      = sa;
    AB[72 + (bb*2+o)*9+t] = sb;
  }
}

// ---------------------------------------------------------------------------
// Kernel C: out[b,o] = x[b,o] + conv3x3(x0;A[b,o]) + conv3x3(x1;B[b,o]).
// 4 pixels/thread, float4 I/O. 512 blocks x 256 thr.
// ---------------------------------------------------------------------------
__global__ __launch_bounds__(256,1) void out_kernel(const float* __restrict__ x,
                                                    const float* __restrict__ AB,
                                                    float* __restrict__ out){
  const int idx = blockIdx.x*256 + threadIdx.x;   // 131072
  const int b  = idx >> 16;
  const int y  = (idx >> 7) & (IMG-1);
  const int xc = (idx & 127) << 2;
  const float* x0 = x + (size_t)b*2*NPIX;
  const float* x1 = x0 + NPIX;

  float A0[9],A1[9],B0[9],B1[9];
#pragma unroll
  for (int t=0;t<9;t++){
    A0[t]=AB[(b*2+0)*9+t];      A1[t]=AB[(b*2+1)*9+t];
    B0[t]=AB[72+(b*2+0)*9+t];   B1[t]=AB[72+(b*2+1)*9+t];
  }
  float v0[3][6], v1[3][6];
#pragma unroll
  for (int r=0;r<3;r++){
    const int yy=y-1+r;
    if ((unsigned)yy < (unsigned)IMG){
      const float* p0=x0+(size_t)yy*IMG;
      const float* p1=x1+(size_t)yy*IMG;
      const float4 m0=*(const float4*)(p0+xc);
      const float4 m1=*(const float4*)(p1+xc);
      v0[r][1]=m0.x; v0[r][2]=m0.y; v0[r][3]=m0.z; v0[r][4]=m0.w;
      v1[r][1]=m1.x; v1[r][2]=m1.y; v1[r][3]=m1.z; v1[r][4]=m1.w;
      v0[r][0]=(xc>0)?p0[xc-1]:0.f;        v1[r][0]=(xc>0)?p1[xc-1]:0.f;
      v0[r][5]=(xc+4<IMG)?p0[xc+4]:0.f;    v1[r][5]=(xc+4<IMG)?p1[xc+4]:0.f;
    } else {
#pragma unroll
      for (int c2=0;c2<6;c2++){v0[r][c2]=0.f;v1[r][c2]=0.f;}
    }
  }
  float res0[4], res1[4];
#pragma unroll
  for (int i=0;i<4;i++){
    float s0=v0[1][i+1];   // + x[b,0,y,x]
    float s1=v1[1][i+1];   // + x[b,1,y,x]
#pragma unroll
    for (int t=0;t<9;t++){
      const int ty=t/3, tx=t%3;
      const float g0=v0[ty][i+tx], g1=v1[ty][i+tx];
      s0 += A0[t]*g0 + B0[t]*g1;
      s1 += A1[t]*g0 + B1[t]*g1;
    }
    res0[i]=s0; res1[i]=s1;
  }
  float* o0p = out + ((size_t)(b*2+0)*IMG + y)*IMG + xc;
  float* o1p = out + ((size_t)(b*2+1)*IMG + y)*IMG + xc;
  *(float4*)o0p = make_float4(res0[0],res0[1],res0[2],res0[3]);
  *(float4*)o1p = make_float4(res1[0],res1[1],res1[2],res1[3]);
}

extern "C" void kernel_launch(void* const* d_in, const int* in_sizes, int n_in,
                              void* d_out, int out_size, void* d_ws, size_t ws_size,
                              hipStream_t stream){
  const float* x       = (const float*)d_in[0];
  const float* e       = (const float*)d_in[1];
  const float* w_conv1 = (const float*)d_in[2];
  const float* w_dw    = (const float*)d_in[3];
  const float* w_ehead = (const float*)d_in[4];
  const float* w_proj  = (const float*)d_in[5];
  const float* a1      = (const float*)d_in[6];
  float* ws   = (float*)d_ws;
  float* part = ws;            // 640*32 = 20480 floats
  float* AB   = ws + 20480;    // 144 floats
  float* out  = (float*)d_out;

  hipLaunchKernelGGL(gram_kernel, dim3(64,5,2), dim3(256), 0, stream, x, e, part);
  hipLaunchKernelGGL(attn_kernel, dim3(1),      dim3(256), 0, stream, part,
                     w_conv1, w_dw, w_ehead, w_proj, a1, AB);
  hipLaunchKernelGGL(out_kernel,  dim3(512),    dim3(256), 0, stream, x, AB, out);
}